// Round 8
// baseline (385.004 us; speedup 1.0000x reference)
//
#include <hip/hip_runtime.h>
#include <math.h>

#define Bb 4
#define Tt 2048
#define Cc 1024
#define Hh 16
#define Dd 64
#define QSC 0.18033688011112042f   // (1/sqrt(64)) * log2(e)

typedef unsigned short ushort_t;
typedef __attribute__((ext_vector_type(8))) short short8;
typedef __attribute__((ext_vector_type(4))) float floatx4;

typedef unsigned int __attribute__((address_space(1))) u32_as1;
typedef unsigned int __attribute__((address_space(3))) u32_as3;

__device__ __forceinline__ void gld_lds16(const void* g, const void* lds_uniform) {
    __builtin_amdgcn_global_load_lds(
        (const u32_as1*)(unsigned long long)g,
        (u32_as3*)(unsigned int)(unsigned long long)lds_uniform,
        16, 0, 0);
}

__device__ inline ushort_t f2bf(float x) {
    unsigned int u = __float_as_uint(x);
    return (ushort_t)((u + 0x7FFFu + ((u >> 16) & 1u)) >> 16);
}

// ---------------- x fp32 -> bf16 ----------------
__global__ __launch_bounds__(256) void convert_kernel(
    const float* __restrict__ in, ushort_t* __restrict__ out, int n4)
{
    int i = blockIdx.x * 256 + threadIdx.x;
    if (i < n4) {
        float4 v = *(const float4*)&in[i * 4];
        ushort_t o[4] = {f2bf(v.x), f2bf(v.y), f2bf(v.z), f2bf(v.w)};
        *(uint2*)&out[i * 4] = *(uint2*)o;
    }
}

// ---------------- W [K][N] fp32 -> Wt [N][K] bf16 ----------------
__global__ __launch_bounds__(256) void transpose_kernel(
    const float* __restrict__ W, ushort_t* __restrict__ Wt, int K, int N)
{
    __shared__ ushort_t Ts[16][72];
    const int n0 = blockIdx.x * 64;
    const int k0 = blockIdx.y * 16;
    const int t = threadIdx.x;
#pragma unroll
    for (int i = 0; i < 4; i++) {
        int e = t + i * 256;
        int kl = e >> 6, nl = e & 63;
        Ts[kl][nl] = f2bf(W[(size_t)(k0 + kl) * N + n0 + nl]);
    }
    __syncthreads();
    {
        int nl = t >> 2, kl4 = (t & 3) * 4;
        ushort_t o[4] = {Ts[kl4][nl], Ts[kl4 + 1][nl], Ts[kl4 + 2][nl], Ts[kl4 + 3][nl]};
        *(uint2*)&Wt[(size_t)(n0 + nl) * K + k0 + kl4] = *(uint2*)o;
    }
}

// ---------------- V part of qkv -> Vg[bh][d][pi(key)] bf16 ----------------
__global__ __launch_bounds__(256) void vtrans_kernel(
    const ushort_t* __restrict__ qkv, ushort_t* __restrict__ Vg)
{
    __shared__ ushort_t Ts[64][67];
    const int t = threadIdx.x;
    const int kt = blockIdx.x;        // 0..31
    const int bh = blockIdx.y;        // 0..63
    const int b = bh >> 4, h = bh & 15;
    const int kbase = kt * 64;
    const int srow = t >> 2, sd0 = (t & 3) * 16;
    const ushort_t* vp = &qkv[(size_t)b * Tt * 3072
                              + (size_t)(kbase + srow) * 3072 + 2048 + h * 64 + sd0];
    ushort_t tv[16];
    *(uint4*)&tv[0] = *(const uint4*)vp;
    *(uint4*)&tv[8] = *(const uint4*)(vp + 8);
#pragma unroll
    for (int j = 0; j < 16; j++) Ts[sd0 + j][srow] = tv[j];
    __syncthreads();
    const int d = t >> 2, c0 = (t & 3) * 16;
    ushort_t o[16];
#pragma unroll
    for (int i = 0; i < 16; i++) {
        int c = c0 + i;
        o[i] = Ts[d][(c >> 2) + (c & 3) * 16];
    }
    ushort_t* op = &Vg[((size_t)bh * 64 + d) * 2048 + kbase + c0];
    *(uint4*)&op[0] = *(uint4*)&o[0];
    *(uint4*)&op[8] = *(uint4*)&o[8];
}

// ---------------- bf16 MFMA GEMM (round-4 structure, untouched) ----------------
template <bool OUT_BF16, bool SCALE_Q>
__global__ __launch_bounds__(256) void gemm_bf16_kernel(
    const ushort_t* __restrict__ A, const ushort_t* __restrict__ Bt,
    const float* __restrict__ bias, void* __restrict__ Co,
    int M, int N, int K)
{
    __shared__ __align__(16) ushort_t As[8192];
    __shared__ __align__(16) ushort_t Bs[8192];

    const int tid = threadIdx.x;
    const int lane = tid & 63;
    const int w = tid >> 6;
    const int q = lane >> 4;
    const int l = lane & 15;
    const int wm = w >> 1, wn = w & 1;

    const int n0 = blockIdx.x * 128;
    const int m0 = blockIdx.y * 128;

    const ushort_t* Ag = A + (size_t)(m0 + l) * K + q * 8;
    const ushort_t* Bg = Bt + (size_t)(n0 + l) * K + q * 8;

    floatx4 acc[4][4];
#pragma unroll
    for (int i = 0; i < 4; i++)
#pragma unroll
        for (int j = 0; j < 4; j++) acc[i][j] = (floatx4){0.f, 0.f, 0.f, 0.f};

    for (int k0 = 0; k0 < K; k0 += 64) {
        __syncthreads();
#pragma unroll
        for (int t = 0; t < 2; t++) {
            const int tg = 2 * w + t;
#pragma unroll
            for (int c = 0; c < 2; c++) {
                gld_lds16(Ag + (size_t)tg * 16 * K + k0 + c * 32, &As[(tg * 2 + c) * 512]);
                gld_lds16(Bg + (size_t)tg * 16 * K + k0 + c * 32, &Bs[(tg * 2 + c) * 512]);
            }
        }
        __syncthreads();

#pragma unroll
        for (int c = 0; c < 2; c++) {
            short8 af[4], bf[4];
#pragma unroll
            for (int mt = 0; mt < 4; mt++)
                af[mt] = *(const short8*)&As[(((wm * 4 + mt) * 2) + c) * 512 + lane * 8];
#pragma unroll
            for (int nt = 0; nt < 4; nt++)
                bf[nt] = *(const short8*)&Bs[(((wn * 4 + nt) * 2) + c) * 512 + lane * 8];
#pragma unroll
            for (int mt = 0; mt < 4; mt++)
#pragma unroll
                for (int nt = 0; nt < 4; nt++)
                    acc[mt][nt] = __builtin_amdgcn_mfma_f32_16x16x32_bf16(
                        af[mt], bf[nt], acc[mt][nt], 0, 0, 0);
        }
    }

    const int rowb = m0 + wm * 64;
    const int colb = n0 + wn * 64;
#pragma unroll
    for (int nt = 0; nt < 4; nt++) {
        const int col = colb + nt * 16 + l;
        const float bi = bias[col];
        const float sc = (SCALE_Q && col < 1024) ? QSC : 1.0f;
#pragma unroll
        for (int mt = 0; mt < 4; mt++) {
#pragma unroll
            for (int r = 0; r < 4; r++) {
                const int row = rowb + mt * 16 + q * 4 + r;
                const float v = (acc[mt][nt][r] + bi) * sc;
                if (OUT_BF16)
                    ((ushort_t*)Co)[(size_t)row * N + col] = f2bf(v);
                else
                    ((float*)Co)[(size_t)row * N + col] = v;
            }
        }
    }
}

// ---------------- bf16 MFMA flash attention, BARRIER-FREE k-loop ----------------
// K/V fragments loaded straight from global into registers (16 B/lane, 64 B
// row segments, L2-resident); no LDS staging, no __syncthreads anywhere.
// Only per-wave P round-trip uses LDS (lgkmcnt, no barrier). Row-sum via
// constant ones B-frag. Grid: x=bh (64), y=q-tile heavy-first (16).
__global__ __launch_bounds__(256, 2) void attn_mfma_kernel(
    const ushort_t* __restrict__ qkv, const ushort_t* __restrict__ Vg,
    ushort_t* __restrict__ yatt)
{
    __shared__ __align__(16) ushort_t Ps[4][16][80]; // per-wave [q][pi(key)]

    const int tid = threadIdx.x;
    const int lane = tid & 63;
    const int w = tid >> 6;
    const int quad = lane >> 4;
    const int l = lane & 15;

    const int qb = 15 - blockIdx.y;            // heavy q-tiles dispatched first
    const int q0 = qb * 128;
    const int bh = blockIdx.x;
    const int b = bh >> 4;
    const int h = bh & 15;
    const size_t base = (size_t)b * Tt * (3 * Cc);
    const int qoff = h * 64;
    const int koff = Cc + h * 64;

    // Q fragments (pre-scaled by QSC in GEMM epilogue)
    short8 Qf[2][2];
#pragma unroll
    for (int mt = 0; mt < 2; mt++)
#pragma unroll
        for (int kc = 0; kc < 2; kc++)
            Qf[mt][kc] = *(const short8*)&qkv[base
                + (size_t)(q0 + mt * 64 + w * 16 + l) * (3 * Cc)
                + qoff + kc * 32 + quad * 8];

    floatx4 Oacc[2][4];
    floatx4 Lacc[2];
#pragma unroll
    for (int mt = 0; mt < 2; mt++) {
        Lacc[mt] = (floatx4){0.f, 0.f, 0.f, 0.f};
#pragma unroll
        for (int dt = 0; dt < 4; dt++)
            Oacc[mt][dt] = (floatx4){0.f, 0.f, 0.f, 0.f};
    }

    const short s1 = (short)0x3F80;   // bf16 1.0
    const short8 ones = {s1, s1, s1, s1, s1, s1, s1, s1};

    // per-lane fragment base addresses:
    // K frag (nt,kc): key = kbase+nt*16+l (row, stride 3072), d = kc*32+quad*8
    const ushort_t* Kg = qkv + base + koff + (size_t)l * (3 * Cc) + quad * 8;
    // V frag (dt,kc): d = dt*16+l (row, stride 2048), picol = kbase+kc*32+quad*8
    const ushort_t* Vgl = Vg + ((size_t)bh * 64 + l) * 2048 + quad * 8;

    const int ntil = 2 * qb + 2;
    for (int kt = 0; kt < ntil; kt++) {
        const int kbase = kt * 64;

        short8 Kf[4][2], Vf[4][2];
#pragma unroll
        for (int nt = 0; nt < 4; nt++)
#pragma unroll
            for (int kc = 0; kc < 2; kc++)
                Kf[nt][kc] = *(const short8*)(Kg
                    + (size_t)(kbase + nt * 16) * (3 * Cc) + kc * 32);
#pragma unroll
        for (int dt = 0; dt < 4; dt++)
#pragma unroll
            for (int kc = 0; kc < 2; kc++)
                Vf[dt][kc] = *(const short8*)(Vgl
                    + (size_t)(dt * 16) * 2048 + kbase + kc * 32);

#pragma unroll
        for (int mt = 0; mt < 2; mt++) {
            const int qmin = q0 + mt * 64 + (w << 4);
            if (kbase > qmin + 15) continue;

            floatx4 S[4];
#pragma unroll
            for (int nt = 0; nt < 4; nt++) S[nt] = (floatx4){0.f, 0.f, 0.f, 0.f};
#pragma unroll
            for (int kc = 0; kc < 2; kc++)
#pragma unroll
                for (int nt = 0; nt < 4; nt++)
                    S[nt] = __builtin_amdgcn_mfma_f32_16x16x32_bf16(
                        Qf[mt][kc], Kf[nt][kc], S[nt], 0, 0, 0);

            const bool need_mask = (kbase + 63 > qmin);

#pragma unroll
            for (int r = 0; r < 4; r++) {
                const int qrow = qmin + quad * 4 + r;
                float e[4];
#pragma unroll
                for (int nt = 0; nt < 4; nt++) {
                    float s = S[nt][r];
                    if (need_mask && (kbase + nt * 16 + l > qrow)) s = -INFINITY;
                    e[nt] = __builtin_amdgcn_exp2f(s);
                }
                unsigned int u0 = __builtin_amdgcn_perm(
                    __float_as_uint(e[1]), __float_as_uint(e[0]), 0x07060302u);
                unsigned int u1 = __builtin_amdgcn_perm(
                    __float_as_uint(e[3]), __float_as_uint(e[2]), 0x07060302u);
                uint2 pk; pk.x = u0; pk.y = u1;
                *(uint2*)&Ps[w][quad * 4 + r][l * 4] = pk;
            }
            asm volatile("" ::: "memory");

            short8 Pa0 = *(const short8*)&Ps[w][l][quad * 8];
            short8 Pa1 = *(const short8*)&Ps[w][l][32 + quad * 8];
#pragma unroll
            for (int dt = 0; dt < 4; dt++) {
                Oacc[mt][dt] = __builtin_amdgcn_mfma_f32_16x16x32_bf16(
                    Pa0, Vf[dt][0], Oacc[mt][dt], 0, 0, 0);
                Oacc[mt][dt] = __builtin_amdgcn_mfma_f32_16x16x32_bf16(
                    Pa1, Vf[dt][1], Oacc[mt][dt], 0, 0, 0);
            }
            Lacc[mt] = __builtin_amdgcn_mfma_f32_16x16x32_bf16(
                Pa0, ones, Lacc[mt], 0, 0, 0);
            Lacc[mt] = __builtin_amdgcn_mfma_f32_16x16x32_bf16(
                Pa1, ones, Lacc[mt], 0, 0, 0);
            asm volatile("" ::: "memory");
        }
    }

#pragma unroll
    for (int mt = 0; mt < 2; mt++)
#pragma unroll
        for (int r = 0; r < 4; r++) {
            const float rl = 1.f / Lacc[mt][r];
            const int qrow = q0 + mt * 64 + (w << 4) + quad * 4 + r;
#pragma unroll
            for (int dt = 0; dt < 4; dt++)
                yatt[(size_t)(b * Tt + qrow) * Cc + h * 64 + dt * 16 + l] =
                    f2bf(Oacc[mt][dt][r] * rl);
        }
}

extern "C" void kernel_launch(void* const* d_in, const int* in_sizes, int n_in,
                              void* d_out, int out_size, void* d_ws, size_t ws_size,
                              hipStream_t stream) {
    const float* x     = (const float*)d_in[0];
    const float* Wqkv  = (const float*)d_in[1];
    const float* bqkv  = (const float*)d_in[2];
    const float* Wproj = (const float*)d_in[3];
    const float* bproj = (const float*)d_in[4];
    float* out = (float*)d_out;

    ushort_t* qkvb   = (ushort_t*)d_ws;                 // 48 MB
    ushort_t* yattb  = qkvb + (size_t)8192 * 3072;      // 16 MB
    ushort_t* xb     = yattb + (size_t)8192 * 1024;     // 16 MB
    ushort_t* wqkvt  = xb + (size_t)8192 * 1024;        // 6 MB
    ushort_t* wprojt = wqkvt + (size_t)3072 * 1024;     // 2 MB
    ushort_t* vg     = wprojt + (size_t)1024 * 1024;    // 16 MB

    convert_kernel<<<(8192 * 1024 / 4 + 255) / 256, 256, 0, stream>>>(x, xb, 8192 * 1024 / 4);
    transpose_kernel<<<dim3(3072 / 64, 1024 / 16), 256, 0, stream>>>(Wqkv, wqkvt, 1024, 3072);
    transpose_kernel<<<dim3(1024 / 64, 1024 / 16), 256, 0, stream>>>(Wproj, wprojt, 1024, 1024);

    gemm_bf16_kernel<true, true><<<dim3(3072 / 128, 8192 / 128), 256, 0, stream>>>(
        xb, wqkvt, bqkv, qkvb, 8192, 3072, 1024);
    vtrans_kernel<<<dim3(Tt / 64, Bb * Hh), 256, 0, stream>>>(qkvb, vg);
    attn_mfma_kernel<<<dim3(Bb * Hh, 16), 256, 0, stream>>>(qkvb, vg, yattb);
    gemm_bf16_kernel<false, false><<<dim3(1024 / 128, 8192 / 128), 256, 0, stream>>>(
        yattb, wprojt, bproj, out, 8192, 1024, 1024);
}